// Round 1
// baseline (1399.683 us; speedup 1.0000x reference)
//
#include <hip/hip_runtime.h>
#include <cstdint>
#include <cstddef>

#define Bsz 8
#define Tsz 200
#define Usz 50
#define Kd  512
#define G4h 2048
#define OD  1000

typedef __attribute__((ext_vector_type(8))) short short8;
typedef __attribute__((ext_vector_type(4))) float f32x4;

__device__ __forceinline__ unsigned short f2bf(float x) {
  union { float f; unsigned u; } v; v.f = x;
  unsigned r = v.u + 0x7FFFu + ((v.u >> 16) & 1u);
  return (unsigned short)(r >> 16);
}
__device__ __forceinline__ float ftanh(float x) {
  float ax = fabsf(x);
  float t = __expf(-2.0f * ax);
  float r = (1.0f - t) / (1.0f + t);
  return copysignf(r, x);
}
__device__ __forceinline__ float sigf(float x) {
  return 1.0f / (1.0f + __expf(-x));
}

__global__ void k_zero(float* p, int n) {
  int i = blockIdx.x * blockDim.x + threadIdx.x;
  if (i < n) p[i] = 0.0f;
}

// eys[u][b][k] = emb[ys[b][u]][k], row 0 (blank) zeroed
__global__ __launch_bounds__(256) void k_embed(const int* __restrict__ ys,
                                               const float* __restrict__ emb,
                                               float* __restrict__ eys) {
  int ub = blockIdx.x;           // u*8 + b
  int u = ub >> 3, b = ub & 7;
  int idx = ys[b * Usz + u];
  float* dst = eys + (size_t)ub * Kd;
  if (idx == 0) {
    for (int k = threadIdx.x; k < Kd; k += 256) dst[k] = 0.0f;
  } else {
    const float* src = emb + (size_t)idx * Kd;
    for (int k = threadIdx.x; k < Kd; k += 256) dst[k] = src[k];
  }
}

// C[M][N] = A[M][512] @ W[N][512]^T + b1 + b2   (fp32, small GEMMs)
__global__ __launch_bounds__(256) void k_gemm(const float* __restrict__ A,
                                              const float* __restrict__ W,
                                              const float* __restrict__ b1,
                                              const float* __restrict__ b2,
                                              float* __restrict__ C, int N) {
  __shared__ float Al[16 * 516];
  int m0 = blockIdx.x * 16;
  int n0 = blockIdx.y * 64;
  for (int i = threadIdx.x; i < 16 * 512; i += 256) {
    int r = i >> 9, k = i & 511;
    Al[r * 516 + k] = A[(size_t)(m0 + r) * Kd + k];
  }
  __syncthreads();
  int nl = threadIdx.x & 63;
  int mg = (threadIdx.x >> 6) * 4;
  int n = n0 + nl;
  const float* Wr = W + (size_t)n * Kd;
  float acc[4] = {0.f, 0.f, 0.f, 0.f};
  #pragma unroll 4
  for (int k = 0; k < 512; k += 4) {
    float4 w = *(const float4*)(Wr + k);
    #pragma unroll
    for (int j = 0; j < 4; ++j) {
      const float* ar = &Al[(mg + j) * 516 + k];
      acc[j] += ar[0] * w.x + ar[1] * w.y + ar[2] * w.z + ar[3] * w.w;
    }
  }
  float bias = (b1 ? b1[n] : 0.0f) + (b2 ? b2[n] : 0.0f);
  #pragma unroll
  for (int j = 0; j < 4; ++j)
    C[(size_t)(m0 + mg + j) * N + n] = acc[j] + bias;
}

// LSTM layer 0, one step: gates = xg(precomputed) + h_in @ Whh^T
__global__ __launch_bounds__(256) void k_lstm0(const float* __restrict__ Whh,
                                               const float* __restrict__ xg,
                                               const float* __restrict__ h_in,
                                               float* __restrict__ h_out,
                                               float* __restrict__ c) {
  __shared__ float hl[8 * 516];
  __shared__ float part[256];
  __shared__ float gl[64];
  for (int i = threadIdx.x; i < 8 * 512; i += 256) {
    int b = i >> 9, k = i & 511;
    hl[b * 516 + k] = h_in[b * 512 + k];
  }
  __syncthreads();
  int ks = threadIdx.x & 3;
  int b = (threadIdx.x >> 2) & 7;
  int g = (threadIdx.x >> 5) & 3;
  int jl = (threadIdx.x >> 7) & 1;
  int j = blockIdx.x * 2 + jl;
  const float* wr = Whh + (size_t)(g * 512 + j) * Kd + ks * 128;
  const float* hr = hl + b * 516 + ks * 128;
  float acc = 0.f;
  #pragma unroll 8
  for (int k = 0; k < 128; k += 4) {
    float4 w = *(const float4*)(wr + k);
    float4 h = *(const float4*)(hr + k);
    acc += w.x * h.x + w.y * h.y + w.z * h.z + w.w * h.w;
  }
  part[threadIdx.x] = acc;
  __syncthreads();
  if (threadIdx.x < 64) {
    int t = threadIdx.x;
    int jl2 = t >> 5, g2 = (t >> 3) & 3, b2 = t & 7;
    int base = (jl2 << 7) + (g2 << 5) + (b2 << 2);
    float s = part[base] + part[base + 1] + part[base + 2] + part[base + 3];
    s += xg[b2 * G4h + g2 * 512 + blockIdx.x * 2 + jl2];
    gl[t] = s;
  }
  __syncthreads();
  if (threadIdx.x < 16) {
    int jl2 = threadIdx.x >> 3, b2 = threadIdx.x & 7;
    int j2 = blockIdx.x * 2 + jl2;
    float gi = gl[jl2 * 32 + b2];
    float gf = gl[jl2 * 32 + 8 + b2];
    float gg = gl[jl2 * 32 + 16 + b2];
    float go = gl[jl2 * 32 + 24 + b2];
    float cold = c[b2 * 512 + j2];
    float cn = sigf(gf) * cold + sigf(gi) * ftanh(gg);
    float hn = sigf(go) * ftanh(cn);
    c[b2 * 512 + j2] = cn;
    h_out[b2 * 512 + j2] = hn;
  }
}

// LSTM layer 1, one step: gates = h0n @ Wih^T + h1_in @ Whh^T + bi + bh
__global__ __launch_bounds__(256) void k_lstm1(const float* __restrict__ Wih,
                                               const float* __restrict__ Whh,
                                               const float* __restrict__ bi,
                                               const float* __restrict__ bh,
                                               const float* __restrict__ h0n,
                                               const float* __restrict__ h1_in,
                                               float* __restrict__ h1_out,
                                               float* __restrict__ c,
                                               float* __restrict__ hdec, int u) {
  __shared__ float hl[2 * 8 * 516];
  __shared__ float part[256];
  __shared__ float gl[64];
  for (int i = threadIdx.x; i < 8 * 512; i += 256) {
    int b = i >> 9, k = i & 511;
    hl[b * 516 + k] = h0n[b * 512 + k];
    hl[8 * 516 + b * 516 + k] = h1_in[b * 512 + k];
  }
  __syncthreads();
  int ks = threadIdx.x & 3;
  int b = (threadIdx.x >> 2) & 7;
  int g = (threadIdx.x >> 5) & 3;
  int jl = (threadIdx.x >> 7) & 1;
  int j = blockIdx.x * 2 + jl;
  const float* wr0 = Wih + (size_t)(g * 512 + j) * Kd + ks * 128;
  const float* wr1 = Whh + (size_t)(g * 512 + j) * Kd + ks * 128;
  const float* hr0 = hl + b * 516 + ks * 128;
  const float* hr1 = hl + 8 * 516 + b * 516 + ks * 128;
  float acc = 0.f;
  #pragma unroll 4
  for (int k = 0; k < 128; k += 4) {
    float4 w0 = *(const float4*)(wr0 + k);
    float4 h0 = *(const float4*)(hr0 + k);
    float4 w1 = *(const float4*)(wr1 + k);
    float4 h1 = *(const float4*)(hr1 + k);
    acc += w0.x * h0.x + w0.y * h0.y + w0.z * h0.z + w0.w * h0.w;
    acc += w1.x * h1.x + w1.y * h1.y + w1.z * h1.z + w1.w * h1.w;
  }
  part[threadIdx.x] = acc;
  __syncthreads();
  if (threadIdx.x < 64) {
    int t = threadIdx.x;
    int jl2 = t >> 5, g2 = (t >> 3) & 3, b2 = t & 7;
    int base = (jl2 << 7) + (g2 << 5) + (b2 << 2);
    float s = part[base] + part[base + 1] + part[base + 2] + part[base + 3];
    int gj = g2 * 512 + blockIdx.x * 2 + jl2;
    s += bi[gj] + bh[gj];
    gl[t] = s;
  }
  __syncthreads();
  if (threadIdx.x < 16) {
    int jl2 = threadIdx.x >> 3, b2 = threadIdx.x & 7;
    int j2 = blockIdx.x * 2 + jl2;
    float gi = gl[jl2 * 32 + b2];
    float gf = gl[jl2 * 32 + 8 + b2];
    float gg = gl[jl2 * 32 + 16 + b2];
    float go = gl[jl2 * 32 + 24 + b2];
    float cold = c[b2 * 512 + j2];
    float cn = sigf(gf) * cold + sigf(gi) * ftanh(gg);
    float hn = sigf(go) * ftanh(cn);
    c[b2 * 512 + j2] = cn;
    h1_out[b2 * 512 + j2] = hn;
    hdec[((size_t)b2 * Usz + u) * Kd + j2] = hn;
  }
}

// W_out fp32 -> bf16, padded to 1008 rows (zeros)
__global__ __launch_bounds__(256) void k_wcvt(const float* __restrict__ W,
                                              unsigned short* __restrict__ Wb) {
  int idx = blockIdx.x * 256 + threadIdx.x;   // < 1008*512
  int n = idx >> 9;
  float v = (n < OD) ? W[idx] : 0.0f;
  Wb[idx] = f2bf(v);
}

// out[m][n] = tanh(z_enc[b,t]+z_dec[b,u]) @ Wout^T + b_out
// m-tile 64 (4 waves x 16 rows), n-tiles of 16, K=512 fully in A-frags (regs)
__global__ __launch_bounds__(256) void k_joint(const float* __restrict__ zenc,
                                               const float* __restrict__ zdec,
                                               const unsigned short* __restrict__ Wb,
                                               const float* __restrict__ bout,
                                               float* __restrict__ out) {
  __shared__ unsigned short Blds[16 * 520];   // +8 pad: 2-way bank alias only
  int lane = threadIdx.x & 63;
  int wv = threadIdx.x >> 6;
  int kgrp = lane >> 4;
  int rl = lane & 15;
  int row = blockIdx.x * 64 + wv * 16 + rl;
  int u = row % Usz;
  int bt = row / Usz;                          // b*T + t
  const float* ze = zenc + (size_t)bt * Kd;
  const float* zd = zdec + (size_t)((bt / Tsz) * Usz + u) * Kd;
  short8 a[16];
  #pragma unroll
  for (int kk = 0; kk < 16; ++kk) {
    int k0 = kk * 32 + kgrp * 8;
    float4 e0 = *(const float4*)(ze + k0);
    float4 e1 = *(const float4*)(ze + k0 + 4);
    float4 d0 = *(const float4*)(zd + k0);
    float4 d1 = *(const float4*)(zd + k0 + 4);
    short8 t;
    t[0] = (short)f2bf(ftanh(e0.x + d0.x));
    t[1] = (short)f2bf(ftanh(e0.y + d0.y));
    t[2] = (short)f2bf(ftanh(e0.z + d0.z));
    t[3] = (short)f2bf(ftanh(e0.w + d0.w));
    t[4] = (short)f2bf(ftanh(e1.x + d1.x));
    t[5] = (short)f2bf(ftanh(e1.y + d1.y));
    t[6] = (short)f2bf(ftanh(e1.z + d1.z));
    t[7] = (short)f2bf(ftanh(e1.w + d1.w));
    a[kk] = t;
  }
  int stc = threadIdx.x >> 4;       // staging row 0..15
  int sto = threadIdx.x & 15;       // staging 64B chunk 0..15
  for (int nt = 0; nt < 63; ++nt) {
    int n0 = nt * 16;
    __syncthreads();
    {
      const int4* src = (const int4*)(Wb + (size_t)(n0 + stc) * Kd + sto * 32);
      int4* dst = (int4*)(&Blds[stc * 520 + sto * 32]);
      dst[0] = src[0]; dst[1] = src[1]; dst[2] = src[2]; dst[3] = src[3];
    }
    __syncthreads();
    f32x4 acc = {0.f, 0.f, 0.f, 0.f};
    const unsigned short* bb = &Blds[rl * 520 + kgrp * 8];
    #pragma unroll
    for (int kk = 0; kk < 16; ++kk) {
      short8 bfr = *(const short8*)(bb + kk * 32);
      acc = __builtin_amdgcn_mfma_f32_16x16x32_bf16(a[kk], bfr, acc, 0, 0, 0);
    }
    int n = n0 + rl;
    if (n < OD) {
      float bo = bout[n];
      size_t base = (size_t)(blockIdx.x * 64 + wv * 16 + kgrp * 4) * OD + n;
      out[base] = acc[0] + bo;
      out[base + OD] = acc[1] + bo;
      out[base + 2 * (size_t)OD] = acc[2] + bo;
      out[base + 3 * (size_t)OD] = acc[3] + bo;
    }
  }
}

extern "C" void kernel_launch(void* const* d_in, const int* in_sizes, int n_in,
                              void* d_out, int out_size, void* d_ws, size_t ws_size,
                              hipStream_t stream) {
  const float* hs   = (const float*)d_in[0];
  const int*   ys   = (const int*)d_in[1];
  const float* emb  = (const float*)d_in[2];
  const float* Wih0 = (const float*)d_in[3];
  const float* Whh0 = (const float*)d_in[4];
  const float* bih0 = (const float*)d_in[5];
  const float* bhh0 = (const float*)d_in[6];
  const float* Wih1 = (const float*)d_in[7];
  const float* Whh1 = (const float*)d_in[8];
  const float* bih1 = (const float*)d_in[9];
  const float* bhh1 = (const float*)d_in[10];
  const float* Wenc = (const float*)d_in[11];
  const float* benc = (const float*)d_in[12];
  const float* Wdec = (const float*)d_in[13];
  const float* Wout = (const float*)d_in[14];
  const float* bout = (const float*)d_in[15];
  float* out = (float*)d_out;

  float* ws   = (float*)d_ws;
  float* eys  = ws;                 // 204800 f
  float* xg0  = ws + 204800;        // 819200 f  [u][b][2048]
  float* h0   = ws + 1024000;       // 8192 f (2 buffers)
  float* h1   = ws + 1032192;       // 8192 f
  float* c0   = ws + 1040384;       // 4096 f
  float* c1   = ws + 1044480;       // 4096 f
  float* hdec = ws + 1048576;       // 204800 f  [b][u][512]
  float* zenc = ws + 1253376;       // 819200 f  [b*T+t][512]
  float* zdec = ws + 2072576;       // 204800 f  [b*U+u][512]
  unsigned short* Wb = (unsigned short*)(ws + 2277376);  // 1008*512 bf16

  k_zero<<<96, 256, 0, stream>>>(h0, 24576);  // h0,h1,c0,c1 contiguous
  k_embed<<<400, 256, 0, stream>>>(ys, emb, eys);
  k_gemm<<<dim3(25, 32), 256, 0, stream>>>(eys, Wih0, bih0, bhh0, xg0, G4h);
  k_gemm<<<dim3(100, 8), 256, 0, stream>>>(hs, Wenc, benc, nullptr, zenc, 512);
  k_wcvt<<<2016, 256, 0, stream>>>(Wout, Wb);

  float* h0a = h0;  float* h0b = h0 + 4096;
  float* h1a = h1;  float* h1b = h1 + 4096;
  for (int u = 0; u < Usz; ++u) {
    const float* h0r = (u & 1) ? h0b : h0a;
    float* h0w       = (u & 1) ? h0a : h0b;
    const float* h1r = (u & 1) ? h1b : h1a;
    float* h1w       = (u & 1) ? h1a : h1b;
    k_lstm0<<<256, 256, 0, stream>>>(Whh0, xg0 + (size_t)u * 8 * G4h, h0r, h0w, c0);
    k_lstm1<<<256, 256, 0, stream>>>(Wih1, Whh1, bih1, bhh1, h0w, h1r, h1w, c1, hdec, u);
  }
  k_gemm<<<dim3(25, 8), 256, 0, stream>>>(hdec, Wdec, nullptr, nullptr, zdec, 512);
  k_joint<<<1250, 256, 0, stream>>>(zenc, zdec, Wb, bout, out);
}

// Round 2
// 1154.967 us; speedup vs baseline: 1.2119x; 1.2119x over previous
//
#include <hip/hip_runtime.h>
#include <cstdint>
#include <cstddef>

#define Bsz 8
#define Tsz 200
#define Usz 50
#define Kd  512
#define G4h 2048
#define OD  1000
#define NBLK 192   // persistent LSTM blocks: 64 A (layer0) + 128 B (layer1)

typedef __attribute__((ext_vector_type(8))) short short8;
typedef __attribute__((ext_vector_type(4))) float f32x4;

__device__ __forceinline__ unsigned short f2bf(float x) {
  union { float f; unsigned u; } v; v.f = x;
  unsigned r = v.u + 0x7FFFu + ((v.u >> 16) & 1u);
  return (unsigned short)(r >> 16);
}
__device__ __forceinline__ float ftanh(float x) {
  float ax = fabsf(x);
  float t = __expf(-2.0f * ax);
  float r = (1.0f - t) / (1.0f + t);
  return copysignf(r, x);
}
__device__ __forceinline__ float sigf(float x) {
  return 1.0f / (1.0f + __expf(-x));
}

// zero h0_seq[0], h1_seq[0], barrier counter
__global__ __launch_bounds__(256) void k_init(float* __restrict__ h0s,
                                              float* __restrict__ h1s,
                                              int* __restrict__ cnt) {
  int i = blockIdx.x * 256 + threadIdx.x;
  if (i < 4096) { h0s[i] = 0.0f; h1s[i] = 0.0f; }
  if (i == 0) *cnt = 0;
}

// eys[u][b][k] = emb[ys[b][u]][k], row 0 (blank) zeroed
__global__ __launch_bounds__(256) void k_embed(const int* __restrict__ ys,
                                               const float* __restrict__ emb,
                                               float* __restrict__ eys) {
  int ub = blockIdx.x;           // u*8 + b
  int u = ub >> 3, b = ub & 7;
  int idx = ys[b * Usz + u];
  float* dst = eys + (size_t)ub * Kd;
  if (idx == 0) {
    for (int k = threadIdx.x; k < Kd; k += 256) dst[k] = 0.0f;
  } else {
    const float* src = emb + (size_t)idx * Kd;
    for (int k = threadIdx.x; k < Kd; k += 256) dst[k] = src[k];
  }
}

// C[M][N] = A[M][512] @ W[N][512]^T + b1 + b2   (fp32, small GEMMs)
__global__ __launch_bounds__(256) void k_gemm(const float* __restrict__ A,
                                              const float* __restrict__ W,
                                              const float* __restrict__ b1,
                                              const float* __restrict__ b2,
                                              float* __restrict__ C, int N) {
  __shared__ float Al[16 * 516];
  int m0 = blockIdx.x * 16;
  int n0 = blockIdx.y * 64;
  for (int i = threadIdx.x; i < 16 * 512; i += 256) {
    int r = i >> 9, k = i & 511;
    Al[r * 516 + k] = A[(size_t)(m0 + r) * Kd + k];
  }
  __syncthreads();
  int nl = threadIdx.x & 63;
  int mg = (threadIdx.x >> 6) * 4;
  int n = n0 + nl;
  const float* Wr = W + (size_t)n * Kd;
  float acc[4] = {0.f, 0.f, 0.f, 0.f};
  #pragma unroll 4
  for (int k = 0; k < 512; k += 4) {
    float4 w = *(const float4*)(Wr + k);
    #pragma unroll
    for (int j = 0; j < 4; ++j) {
      const float* ar = &Al[(mg + j) * 516 + k];
      acc[j] += ar[0] * w.x + ar[1] * w.y + ar[2] * w.z + ar[3] * w.w;
    }
  }
  float bias = (b1 ? b1[n] : 0.0f) + (b2 ? b2[n] : 0.0f);
  #pragma unroll
  for (int j = 0; j < 4; ++j)
    C[(size_t)(m0 + mg + j) * N + n] = acc[j] + bias;
}

// ---------- persistent 2-layer LSTM over all 50 steps, one dispatch ----------
// blocks 0..63   (A): layer0, 8 j-cols each; gates = xg0[u] + h0 @ Whh0^T
// blocks 64..191 (B): layer1, 4 j-cols each; gates = h0 @ Wih1^T + h1 @ Whh1^T + bi + bh
// h exchanged via h0_seq/h1_seq (index = step+1; slot 0 = zero init).
__device__ __forceinline__ void gridbar(int* cnt, int target) {
  __syncthreads();
  if (threadIdx.x == 0) {
    __threadfence();                      // release: flush block's writes device-wide
    atomicAdd(cnt, 1);
    while (__hip_atomic_load(cnt, __ATOMIC_RELAXED, __HIP_MEMORY_SCOPE_AGENT) < target) {
      __builtin_amdgcn_s_sleep(2);
    }
    __threadfence();                      // acquire: invalidate stale caches
  }
  __syncthreads();
}

__global__ __launch_bounds__(256) void k_lstm_all(
    const float* __restrict__ Whh0, const float* __restrict__ Wih1,
    const float* __restrict__ Whh1, const float* __restrict__ bih1,
    const float* __restrict__ bhh1, const float* __restrict__ xg0,
    float* __restrict__ h0_seq, float* __restrict__ h1_seq,
    float* __restrict__ hdec, int* __restrict__ cnt) {
  __shared__ float lds[20800];            // 83.2 KB static LDS
  float* wA    = lds;                     // A: 32x512 | B: Wih 16x512, Whh 16x512 @+8192
  float* hst   = lds + 16384;             // 4096 floats staged h
  float* gates = lds + 20480;             // up to 256
  float* cst   = lds + 20736;             // 64 cell states

  const int bid = blockIdx.x;
  const int t = threadIdx.x;
  const bool isA = bid < 64;

  if (isA) {
    int j0 = bid * 8;
    for (int i = t; i < 32 * 128; i += 256) {          // 32 rows x 128 float4
      int row = i >> 7, kc = i & 127;
      int g = row >> 3, jl = row & 7;
      *(float4*)&wA[row * 512 + kc * 4] =
          *(const float4*)&Whh0[((size_t)(g * 512 + j0 + jl)) * Kd + kc * 4];
    }
  } else {
    int j0 = (bid - 64) * 4;
    for (int i = t; i < 16 * 128; i += 256) {          // 16 rows x 128 float4
      int row = i >> 7, kc = i & 127;
      int g = row >> 2, jl = row & 3;
      size_t gr = ((size_t)(g * 512 + j0 + jl)) * Kd + kc * 4;
      *(float4*)&wA[row * 512 + kc * 4] = *(const float4*)&Wih1[gr];
      *(float4*)&wA[8192 + row * 512 + kc * 4] = *(const float4*)&Whh1[gr];
    }
  }
  if (t < 64) cst[t] = 0.0f;
  __syncthreads();

  for (int p = 0; p <= 50; ++p) {
    if (isA) {
      if (p < 50) {
        const float* hsrc = h0_seq + (size_t)p * 4096;
        #pragma unroll
        for (int q = 0; q < 4; ++q) {
          int idx = q * 1024 + t * 4;
          *(float4*)&hst[idx] = *(const float4*)&hsrc[idx];
        }
        __syncthreads();
        int row = (t >> 6) * 8 + ((t & 63) >> 3);      // 0..31 (= g*8 + jl)
        int ks = t & 7;
        float acc[8] = {0.f, 0.f, 0.f, 0.f, 0.f, 0.f, 0.f, 0.f};
        #pragma unroll
        for (int kk = 0; kk < 16; ++kk) {
          int c = kk * 8 + ks;                         // interleaved k-chunks
          float4 w = *(const float4*)&wA[row * 512 + c * 4];
          #pragma unroll
          for (int b = 0; b < 8; ++b) {
            float4 h = *(const float4*)&hst[b * 512 + c * 4];
            acc[b] += w.x * h.x + w.y * h.y + w.z * h.z + w.w * h.w;
          }
        }
        #pragma unroll
        for (int b = 0; b < 8; ++b) {
          acc[b] += __shfl_xor(acc[b], 1);
          acc[b] += __shfl_xor(acc[b], 2);
          acc[b] += __shfl_xor(acc[b], 4);
        }
        if (ks == 0) {
          #pragma unroll
          for (int b = 0; b < 8; ++b) gates[row * 8 + b] = acc[b];
        }
        __syncthreads();
        if (t < 64) {
          int jl = t >> 3, b = t & 7;
          int j0 = bid * 8;
          const float* xgp = xg0 + ((size_t)p * 8 + b) * G4h + j0 + jl;
          float gi = gates[(jl) * 8 + b]      + xgp[0];
          float gf = gates[(8 + jl) * 8 + b]  + xgp[512];
          float gg = gates[(16 + jl) * 8 + b] + xgp[1024];
          float go = gates[(24 + jl) * 8 + b] + xgp[1536];
          float cold = cst[t];
          float cn = sigf(gf) * cold + sigf(gi) * ftanh(gg);
          float hn = sigf(go) * ftanh(cn);
          cst[t] = cn;
          h0_seq[((size_t)(p + 1)) * 4096 + b * 512 + j0 + jl] = hn;
        }
      }
    } else {
      if (p >= 1) {
        const float* hsrc = h0_seq + (size_t)p * 4096;
        #pragma unroll
        for (int q = 0; q < 4; ++q) {
          int idx = q * 1024 + t * 4;
          *(float4*)&hst[idx] = *(const float4*)&hsrc[idx];
        }
        __syncthreads();
        int row = (t >> 6) * 4 + ((t & 63) >> 4);      // 0..15 (= g*4 + jl)
        int ks = t & 15;
        float acc[8] = {0.f, 0.f, 0.f, 0.f, 0.f, 0.f, 0.f, 0.f};
        #pragma unroll
        for (int kk = 0; kk < 8; ++kk) {
          int c = kk * 16 + ks;
          float4 w = *(const float4*)&wA[row * 512 + c * 4];
          #pragma unroll
          for (int b = 0; b < 8; ++b) {
            float4 h = *(const float4*)&hst[b * 512 + c * 4];
            acc[b] += w.x * h.x + w.y * h.y + w.z * h.z + w.w * h.w;
          }
        }
        __syncthreads();
        const float* hsrc1 = h1_seq + (size_t)(p - 1) * 4096;
        #pragma unroll
        for (int q = 0; q < 4; ++q) {
          int idx = q * 1024 + t * 4;
          *(float4*)&hst[idx] = *(const float4*)&hsrc1[idx];
        }
        __syncthreads();
        #pragma unroll
        for (int kk = 0; kk < 8; ++kk) {
          int c = kk * 16 + ks;
          float4 w = *(const float4*)&wA[8192 + row * 512 + c * 4];
          #pragma unroll
          for (int b = 0; b < 8; ++b) {
            float4 h = *(const float4*)&hst[b * 512 + c * 4];
            acc[b] += w.x * h.x + w.y * h.y + w.z * h.z + w.w * h.w;
          }
        }
        #pragma unroll
        for (int b = 0; b < 8; ++b) {
          acc[b] += __shfl_xor(acc[b], 1);
          acc[b] += __shfl_xor(acc[b], 2);
          acc[b] += __shfl_xor(acc[b], 4);
          acc[b] += __shfl_xor(acc[b], 8);
        }
        if (ks == 0) {
          #pragma unroll
          for (int b = 0; b < 8; ++b) gates[row * 8 + b] = acc[b];
        }
        __syncthreads();
        if (t < 32) {
          int jl = t >> 3, b = t & 7;
          int j0 = (bid - 64) * 4;
          int jg = j0 + jl;
          float gi = gates[(jl) * 8 + b]      + bih1[jg]        + bhh1[jg];
          float gf = gates[(4 + jl) * 8 + b]  + bih1[512 + jg]  + bhh1[512 + jg];
          float gg = gates[(8 + jl) * 8 + b]  + bih1[1024 + jg] + bhh1[1024 + jg];
          float go = gates[(12 + jl) * 8 + b] + bih1[1536 + jg] + bhh1[1536 + jg];
          float cold = cst[t];
          float cn = sigf(gf) * cold + sigf(gi) * ftanh(gg);
          float hn = sigf(go) * ftanh(cn);
          cst[t] = cn;
          h1_seq[(size_t)p * 4096 + b * 512 + jg] = hn;
          hdec[((size_t)b * Usz + (p - 1)) * Kd + jg] = hn;
        }
      }
    }
    if (p < 50) gridbar(cnt, (p + 1) * NBLK);
  }
}

// W_out fp32 -> bf16, padded to 1024 rows (zeros)
__global__ __launch_bounds__(256) void k_wcvt(const float* __restrict__ W,
                                              unsigned short* __restrict__ Wb) {
  int idx = blockIdx.x * 256 + threadIdx.x;   // < 1024*512
  int n = idx >> 9;
  float v = (n < OD) ? W[idx] : 0.0f;
  Wb[idx] = f2bf(v);
}

// out[m][n] = tanh(z_enc[b,t]+z_dec[b,u]) @ Wout^T + b_out
// block = 128 m-rows (4 waves x 32 rows), 32 iterations of 32 n-cols.
// XOR-swizzled LDS (byte ^= (row&7)<<4) kills the bank conflicts;
// B-frag reused across 2 row-groups.
__global__ __launch_bounds__(256, 2) void k_joint(const float* __restrict__ zenc,
                                                  const float* __restrict__ zdec,
                                                  const unsigned short* __restrict__ Wb,
                                                  const float* __restrict__ bout,
                                                  float* __restrict__ out) {
  __shared__ unsigned short Blds[32 * 512];    // 32 KB, swizzled
  int lane = threadIdx.x & 63;
  int wv = threadIdx.x >> 6;
  int kgrp = lane >> 4;
  int rl = lane & 15;
  int rbase = blockIdx.x * 128 + wv * 32;

  short8 a[2][16];
  #pragma unroll
  for (int rg = 0; rg < 2; ++rg) {
    int row = rbase + rg * 16 + rl;
    int u = row % Usz;
    int bt = row / Usz;
    const float* ze = zenc + (size_t)bt * Kd;
    const float* zd = zdec + (size_t)((bt / Tsz) * Usz + u) * Kd;
    #pragma unroll
    for (int kk = 0; kk < 16; ++kk) {
      int k0 = kk * 32 + kgrp * 8;
      float4 e0 = *(const float4*)(ze + k0);
      float4 e1 = *(const float4*)(ze + k0 + 4);
      float4 d0 = *(const float4*)(zd + k0);
      float4 d1 = *(const float4*)(zd + k0 + 4);
      short8 tt;
      tt[0] = (short)f2bf(ftanh(e0.x + d0.x));
      tt[1] = (short)f2bf(ftanh(e0.y + d0.y));
      tt[2] = (short)f2bf(ftanh(e0.z + d0.z));
      tt[3] = (short)f2bf(ftanh(e0.w + d0.w));
      tt[4] = (short)f2bf(ftanh(e1.x + d1.x));
      tt[5] = (short)f2bf(ftanh(e1.y + d1.y));
      tt[6] = (short)f2bf(ftanh(e1.z + d1.z));
      tt[7] = (short)f2bf(ftanh(e1.w + d1.w));
      a[rg][kk] = tt;
    }
  }

  int srow = threadIdx.x >> 3;                  // 0..31 staged row
  int sc0  = threadIdx.x & 7;                   // lane chunk within row
  for (int it = 0; it < 32; ++it) {
    int n0 = it * 32;
    __syncthreads();
    {
      const unsigned short* src = Wb + ((size_t)(n0 + srow) << 9);
      #pragma unroll
      for (int i = 0; i < 8; ++i) {
        int c = sc0 + i * 8;                                   // 16B chunk idx
        int off = ((c * 16) ^ ((srow & 7) << 4)) + srow * 1024; // swizzled byte
        *(int4*)((char*)Blds + off) = *(const int4*)(src + c * 8);
      }
    }
    __syncthreads();
    f32x4 acc00 = {0.f,0.f,0.f,0.f}, acc01 = {0.f,0.f,0.f,0.f};
    f32x4 acc10 = {0.f,0.f,0.f,0.f}, acc11 = {0.f,0.f,0.f,0.f};
    #pragma unroll
    for (int kk = 0; kk < 16; ++kk) {
      int c = kk * 4 + kgrp;
      int b0 = ((c * 16) ^ ((rl & 7) << 4)) + rl * 1024;
      int b1 = ((c * 16) ^ (((rl + 16) & 7) << 4)) + (rl + 16) * 1024;
      short8 bf0 = *(const short8*)((const char*)Blds + b0);
      short8 bf1 = *(const short8*)((const char*)Blds + b1);
      acc00 = __builtin_amdgcn_mfma_f32_16x16x32_bf16(a[0][kk], bf0, acc00, 0, 0, 0);
      acc10 = __builtin_amdgcn_mfma_f32_16x16x32_bf16(a[1][kk], bf0, acc10, 0, 0, 0);
      acc01 = __builtin_amdgcn_mfma_f32_16x16x32_bf16(a[0][kk], bf1, acc01, 0, 0, 0);
      acc11 = __builtin_amdgcn_mfma_f32_16x16x32_bf16(a[1][kk], bf1, acc11, 0, 0, 0);
    }
    #pragma unroll
    for (int nt = 0; nt < 2; ++nt) {
      int n = n0 + nt * 16 + rl;
      if (n < OD) {
        float bo = bout[n];
        const f32x4& A0 = nt ? acc01 : acc00;
        const f32x4& A1 = nt ? acc11 : acc10;
        size_t r0 = (size_t)(rbase + kgrp * 4) * OD + n;
        size_t r1 = (size_t)(rbase + 16 + kgrp * 4) * OD + n;
        #pragma unroll
        for (int j = 0; j < 4; ++j) {
          out[r0 + (size_t)j * OD] = A0[j] + bo;
          out[r1 + (size_t)j * OD] = A1[j] + bo;
        }
      }
    }
  }
}

extern "C" void kernel_launch(void* const* d_in, const int* in_sizes, int n_in,
                              void* d_out, int out_size, void* d_ws, size_t ws_size,
                              hipStream_t stream) {
  const float* hs   = (const float*)d_in[0];
  const int*   ys   = (const int*)d_in[1];
  const float* emb  = (const float*)d_in[2];
  const float* Wih0 = (const float*)d_in[3];
  const float* Whh0 = (const float*)d_in[4];
  const float* bih0 = (const float*)d_in[5];
  const float* bhh0 = (const float*)d_in[6];
  const float* Wih1 = (const float*)d_in[7];
  const float* Whh1 = (const float*)d_in[8];
  const float* bih1 = (const float*)d_in[9];
  const float* bhh1 = (const float*)d_in[10];
  const float* Wenc = (const float*)d_in[11];
  const float* benc = (const float*)d_in[12];
  const float* Wdec = (const float*)d_in[13];
  const float* Wout = (const float*)d_in[14];
  const float* bout = (const float*)d_in[15];
  float* out = (float*)d_out;

  float* ws     = (float*)d_ws;
  float* eys    = ws;                  // 204800
  float* xg0    = ws + 204800;         // 819200  [u][b][2048]
  float* h0_seq = ws + 1024000;        // 51*4096 [step+1][b][512]
  float* h1_seq = ws + 1232896;        // 51*4096
  float* hdec   = ws + 1441792;        // 204800  [b][u][512]
  float* zenc   = ws + 1646592;        // 819200  [b*T+t][512]
  float* zdec   = ws + 2465792;        // 204800  [b*U+u][512]
  unsigned short* Wb = (unsigned short*)(ws + 2670592);  // 1024*512 bf16
  int* cnt      = (int*)(ws + 2932736);

  k_init<<<16, 256, 0, stream>>>(h0_seq, h1_seq, cnt);
  k_embed<<<400, 256, 0, stream>>>(ys, emb, eys);
  k_gemm<<<dim3(25, 32), 256, 0, stream>>>(eys, Wih0, bih0, bhh0, xg0, G4h);
  k_gemm<<<dim3(100, 8), 256, 0, stream>>>(hs, Wenc, benc, nullptr, zenc, 512);
  k_wcvt<<<2048, 256, 0, stream>>>(Wout, Wb);
  k_lstm_all<<<NBLK, 256, 0, stream>>>(Whh0, Wih1, Whh1, bih1, bhh1, xg0,
                                       h0_seq, h1_seq, hdec, cnt);
  k_gemm<<<dim3(25, 8), 256, 0, stream>>>(hdec, Wdec, nullptr, nullptr, zdec, 512);
  k_joint<<<625, 256, 0, stream>>>(zenc, zdec, Wb, bout, out);
}

// Round 4
// 647.963 us; speedup vs baseline: 2.1601x; 1.7825x over previous
//
#include <hip/hip_runtime.h>
#include <cstdint>
#include <cstddef>

#define Tsz 200
#define Usz 50
#define Kd  512
#define G4h 2048
#define OD  1000

typedef __attribute__((ext_vector_type(8))) short short8;
typedef __attribute__((ext_vector_type(4))) float f32x4;

__device__ __forceinline__ unsigned short f2bf(float x) {
  union { float f; unsigned u; } v; v.f = x;
  unsigned r = v.u + 0x7FFFu + ((v.u >> 16) & 1u);
  return (unsigned short)(r >> 16);
}
__device__ __forceinline__ float bf2f(unsigned short h) {
  union { unsigned u; float f; } v; v.u = ((unsigned)h) << 16; return v.f;
}
__device__ __forceinline__ void splits(float w, short& hi, short& lo) {
  unsigned short h = f2bf(w);
  hi = (short)h;
  lo = (short)f2bf(w - bf2f(h));
}
__device__ __forceinline__ void split8(float4 f0, float4 f1, short8& hi, short8& lo) {
  float v[8] = {f0.x, f0.y, f0.z, f0.w, f1.x, f1.y, f1.z, f1.w};
  #pragma unroll
  for (int i = 0; i < 8; ++i) { short a, b2; splits(v[i], a, b2); hi[i] = a; lo[i] = b2; }
}
__device__ __forceinline__ float ftanh(float x) {
  float ax = fabsf(x);
  float t = __expf(-2.0f * ax);
  float r = (1.0f - t) / (1.0f + t);
  return copysignf(r, x);
}
__device__ __forceinline__ float sigf(float x) {
  return 1.0f / (1.0f + __expf(-x));
}
__device__ __forceinline__ unsigned aload(const unsigned* p) {
  return __hip_atomic_load(p, __ATOMIC_RELAXED, __HIP_MEMORY_SCOPE_AGENT);
}
__device__ __forceinline__ void astore(unsigned* p, unsigned v) {
  __hip_atomic_store(p, v, __ATOMIC_RELAXED, __HIP_MEMORY_SCOPE_AGENT);
}
// bounded re-poll for a straggler slot (normal path never loops)
__device__ __forceinline__ unsigned waittag(const unsigned* p, unsigned tag) {
  unsigned v = aload(p);
  int guard = 0;
  while ((v & 0xFFu) != tag && guard < (1 << 22)) {
    __builtin_amdgcn_s_sleep(2);
    v = aload(p);
    ++guard;
  }
  return v;
}

__global__ __launch_bounds__(256) void k_init(unsigned* __restrict__ h0s,
                                              unsigned* __restrict__ h1s) {
  int i = blockIdx.x * 256 + threadIdx.x;
  if (i < 4096) { h0s[i] = 0u; h1s[i] = 0u; }   // f32 0.0 with tag 0
}

// eys[u][b][k] = emb[ys[b][u]][k], row 0 (blank) zeroed
__global__ __launch_bounds__(256) void k_embed(const int* __restrict__ ys,
                                               const float* __restrict__ emb,
                                               float* __restrict__ eys) {
  int ub = blockIdx.x;           // u*8 + b
  int u = ub >> 3, b = ub & 7;
  int idx = ys[b * Usz + u];
  float* dst = eys + (size_t)ub * Kd;
  if (idx == 0) {
    for (int k = threadIdx.x; k < Kd; k += 256) dst[k] = 0.0f;
  } else {
    const float* src = emb + (size_t)idx * Kd;
    for (int k = threadIdx.x; k < Kd; k += 256) dst[k] = src[k];
  }
}

// C[M][N] = A[M][512] @ W[N][512]^T + b1 + b2   (fp32, small GEMMs)
__global__ __launch_bounds__(256) void k_gemm(const float* __restrict__ A,
                                              const float* __restrict__ W,
                                              const float* __restrict__ b1,
                                              const float* __restrict__ b2,
                                              float* __restrict__ C, int N) {
  __shared__ float Al[16 * 516];
  int m0 = blockIdx.x * 16;
  int n0 = blockIdx.y * 64;
  for (int i = threadIdx.x; i < 16 * 512; i += 256) {
    int r = i >> 9, k = i & 511;
    Al[r * 516 + k] = A[(size_t)(m0 + r) * Kd + k];
  }
  __syncthreads();
  int nl = threadIdx.x & 63;
  int mg = (threadIdx.x >> 6) * 4;
  int n = n0 + nl;
  const float* Wr = W + (size_t)n * Kd;
  float acc[4] = {0.f, 0.f, 0.f, 0.f};
  #pragma unroll 4
  for (int k = 0; k < 512; k += 4) {
    float4 w = *(const float4*)(Wr + k);
    #pragma unroll
    for (int j = 0; j < 4; ++j) {
      const float* ar = &Al[(mg + j) * 516 + k];
      acc[j] += ar[0] * w.x + ar[1] * w.y + ar[2] * w.z + ar[3] * w.w;
    }
  }
  float bias = (b1 ? b1[n] : 0.0f) + (b2 ? b2[n] : 0.0f);
  #pragma unroll
  for (int j = 0; j < 4; ++j)
    C[(size_t)(m0 + mg + j) * N + n] = acc[j] + bias;
}

// same gemm but writes xgr[u][jb(32)][g(4)][jl(16)*8 + b] for the LSTM epilogue
__global__ __launch_bounds__(256) void k_gemm_xg(const float* __restrict__ A,
                                                 const float* __restrict__ W,
                                                 const float* __restrict__ b1,
                                                 const float* __restrict__ b2,
                                                 float* __restrict__ C) {
  __shared__ float Al[16 * 516];
  int m0 = blockIdx.x * 16;
  int n0 = blockIdx.y * 64;
  for (int i = threadIdx.x; i < 16 * 512; i += 256) {
    int r = i >> 9, k = i & 511;
    Al[r * 516 + k] = A[(size_t)(m0 + r) * Kd + k];
  }
  __syncthreads();
  int nl = threadIdx.x & 63;
  int mg = (threadIdx.x >> 6) * 4;
  int n = n0 + nl;
  const float* Wr = W + (size_t)n * Kd;
  float acc[4] = {0.f, 0.f, 0.f, 0.f};
  #pragma unroll 4
  for (int k = 0; k < 512; k += 4) {
    float4 w = *(const float4*)(Wr + k);
    #pragma unroll
    for (int j = 0; j < 4; ++j) {
      const float* ar = &Al[(mg + j) * 516 + k];
      acc[j] += ar[0] * w.x + ar[1] * w.y + ar[2] * w.z + ar[3] * w.w;
    }
  }
  float bias = b1[n] + b2[n];
  int g = n >> 9, jc = n & 511;
  #pragma unroll
  for (int j = 0; j < 4; ++j) {
    int m = m0 + mg + j;
    int u = m >> 3, b = m & 7;
    C[(((size_t)u * 32 + (jc >> 4)) * 4 + g) * 128 + (jc & 15) * 8 + b] = acc[j] + bias;
  }
}

// ---------- persistent 2-layer LSTM, fence-free dataflow + MFMA ----------
// blocks 0..31  (A): layer0, 16 j-cols; weights (hi/lo bf16) in VGPRs
// blocks 32..95 (B): layer1, 8 j-cols; Wih1+Whh1 (hi/lo) in VGPRs
// h exchanged via u32 slots: f32 bits with low 8 mantissa bits = step tag.
__global__ __launch_bounds__(256, 1) void k_lstm_all(
    const float* __restrict__ Whh0, const float* __restrict__ Wih1,
    const float* __restrict__ Whh1, const float* __restrict__ bih1,
    const float* __restrict__ bhh1, const float* __restrict__ xgr,
    unsigned* __restrict__ h0s, unsigned* __restrict__ h1s,
    float* __restrict__ hdec) {
  __shared__ __align__(16) unsigned short sd[34816];   // 69.6 KB
  unsigned short* H0H = sd;
  unsigned short* H0L = sd + 8192;
  unsigned short* H1H = sd + 16384;
  unsigned short* H1L = sd + 24576;
  float* gsm = (float*)(sd + 32768);                   // 4 KB: [wv][b16][r16]

  const int tid = threadIdx.x;
  const int lane = tid & 63;
  const int wv = tid >> 6;
  const int bid = blockIdx.x;
  const int sb = tid >> 5;                  // staging batch 0..7
  const int sseg = tid & 31;                // staging k-segment
  const int sbase = sseg * 256 + sb * 8;
  const int kq = lane >> 4;
  const int cl = lane & 15;

  if (bid < 32) {
    // ---------------- layer 0 ----------------
    const int j0 = bid * 16;
    short8 whi[16], wlo[16];
    {
      const float* wr = Whh0 + ((size_t)(wv * 512 + j0 + cl)) * Kd;
      #pragma unroll
      for (int kt = 0; kt < 16; ++kt) {
        const float* p4 = wr + kt * 32 + kq * 8;
        split8(*(const float4*)p4, *(const float4*)(p4 + 4), whi[kt], wlo[kt]);
      }
    }
    float creg = 0.0f;
    const int ejl = tid & 15, eb = tid >> 4;   // epilogue map, tid<128
    for (int p = 0; p < 50; ++p) {
      {
        const unsigned* src = h0s + (size_t)p * 4096 + sb * 512 + sseg * 16;
        unsigned v[16];
        #pragma unroll
        for (int i = 0; i < 16; ++i) v[i] = aload(src + i);
        #pragma unroll
        for (int i = 0; i < 16; ++i)
          if ((v[i] & 0xFFu) != (unsigned)p) v[i] = waittag(src + i, (unsigned)p);
        short8 a0, b0, a1, b1;
        #pragma unroll
        for (int i = 0; i < 8; ++i) {
          short x, y; splits(__uint_as_float(v[i]), x, y);
          a0[i] = x; b0[i] = y;
        }
        #pragma unroll
        for (int i = 0; i < 8; ++i) {
          short x, y; splits(__uint_as_float(v[8 + i]), x, y);
          a1[i] = x; b1[i] = y;
        }
        *(short8*)&H0H[sbase] = a0;        *(short8*)&H0L[sbase] = b0;
        *(short8*)&H0H[sbase + 128] = a1;  *(short8*)&H0L[sbase + 128] = b1;
      }
      __syncthreads();
      f32x4 acc = {0.f, 0.f, 0.f, 0.f};
      #pragma unroll
      for (int kt = 0; kt < 16; ++kt) {
        int e = kt * 512 + kq * 128 + cl * 8;
        short8 bh = *(const short8*)&H0H[e];
        short8 bl = *(const short8*)&H0L[e];
        acc = __builtin_amdgcn_mfma_f32_16x16x32_bf16(whi[kt], bh, acc, 0, 0, 0);
        acc = __builtin_amdgcn_mfma_f32_16x16x32_bf16(wlo[kt], bh, acc, 0, 0, 0);
        acc = __builtin_amdgcn_mfma_f32_16x16x32_bf16(whi[kt], bl, acc, 0, 0, 0);
      }
      *(f32x4*)&gsm[(wv * 16 + cl) * 16 + kq * 4] = acc;
      __syncthreads();
      if (tid < 128) {
        float g0 = gsm[(0 * 16 + eb) * 16 + ejl];
        float g1 = gsm[(1 * 16 + eb) * 16 + ejl];
        float g2 = gsm[(2 * 16 + eb) * 16 + ejl];
        float g3 = gsm[(3 * 16 + eb) * 16 + ejl];
        const float* xp = xgr + (((size_t)p * 32 + bid) * 4) * 128 + ejl * 8 + eb;
        float gi = g0 + xp[0];
        float gf = g1 + xp[128];
        float gg = g2 + xp[256];
        float go = g3 + xp[384];
        float cn = sigf(gf) * creg + sigf(gi) * ftanh(gg);
        float hn = sigf(go) * ftanh(cn);
        creg = cn;
        unsigned hv = (__float_as_uint(hn) & ~0xFFu) | (unsigned)(p + 1);
        astore(h0s + (size_t)(p + 1) * 4096 + eb * 512 + j0 + ejl, hv);
      }
      __syncthreads();
    }
  } else {
    // ---------------- layer 1 ----------------
    const int j0 = (bid - 32) * 8;
    const int mt = wv & 1, kh = wv >> 1;
    short8 wihh[8], wihl[8], whhh[8], whhl[8];
    {
      const int g = mt * 2 + (cl >> 3), jl = cl & 7;
      const float* wr0 = Wih1 + ((size_t)(g * 512 + j0 + jl)) * Kd;
      const float* wr1 = Whh1 + ((size_t)(g * 512 + j0 + jl)) * Kd;
      #pragma unroll
      for (int k2 = 0; k2 < 8; ++k2) {
        int kt = kh * 8 + k2;
        const float* p0 = wr0 + kt * 32 + kq * 8;
        const float* p1 = wr1 + kt * 32 + kq * 8;
        split8(*(const float4*)p0, *(const float4*)(p0 + 4), wihh[k2], wihl[k2]);
        split8(*(const float4*)p1, *(const float4*)(p1 + 4), whhh[k2], whhl[k2]);
      }
    }
    float creg = 0.0f;
    const int ejl = tid & 7, eb = (tid >> 3) & 7;   // tid<64
    float bs0 = bih1[0 * 512 + j0 + ejl] + bhh1[0 * 512 + j0 + ejl];
    float bs1 = bih1[1 * 512 + j0 + ejl] + bhh1[1 * 512 + j0 + ejl];
    float bs2 = bih1[2 * 512 + j0 + ejl] + bhh1[2 * 512 + j0 + ejl];
    float bs3 = bih1[3 * 512 + j0 + ejl] + bhh1[3 * 512 + j0 + ejl];
    for (int p = 1; p <= 50; ++p) {
      {
        const unsigned* s0 = h0s + (size_t)p * 4096 + sb * 512 + sseg * 16;
        const unsigned* s1 = h1s + (size_t)(p - 1) * 4096 + sb * 512 + sseg * 16;
        unsigned v0[16], v1[16];
        #pragma unroll
        for (int i = 0; i < 16; ++i) v0[i] = aload(s0 + i);
        #pragma unroll
        for (int i = 0; i < 16; ++i) v1[i] = aload(s1 + i);
        #pragma unroll
        for (int i = 0; i < 16; ++i)
          if ((v0[i] & 0xFFu) != (unsigned)p) v0[i] = waittag(s0 + i, (unsigned)p);
        #pragma unroll
        for (int i = 0; i < 16; ++i)
          if ((v1[i] & 0xFFu) != (unsigned)(p - 1)) v1[i] = waittag(s1 + i, (unsigned)(p - 1));
        short8 a0, b0, a1, b1, c0, d0, c1, d1;
        #pragma unroll
        for (int i = 0; i < 8; ++i) {
          short x, y;
          splits(__uint_as_float(v0[i]), x, y);     a0[i] = x; b0[i] = y;
          splits(__uint_as_float(v0[8 + i]), x, y); a1[i] = x; b1[i] = y;
          splits(__uint_as_float(v1[i]), x, y);     c0[i] = x; d0[i] = y;
          splits(__uint_as_float(v1[8 + i]), x, y); c1[i] = x; d1[i] = y;
        }
        *(short8*)&H0H[sbase] = a0;        *(short8*)&H0L[sbase] = b0;
        *(short8*)&H0H[sbase + 128] = a1;  *(short8*)&H0L[sbase + 128] = b1;
        *(short8*)&H1H[sbase] = c0;        *(short8*)&H1L[sbase] = d0;
        *(short8*)&H1H[sbase + 128] = c1;  *(short8*)&H1L[sbase + 128] = d1;
      }
      __syncthreads();
      f32x4 acc = {0.f, 0.f, 0.f, 0.f};
      #pragma unroll
      for (int k2 = 0; k2 < 8; ++k2) {
        int kt = kh * 8 + k2;
        int e = kt * 512 + kq * 128 + cl * 8;
        short8 b0h = *(const short8*)&H0H[e];
        short8 b0l = *(const short8*)&H0L[e];
        short8 b1h = *(const short8*)&H1H[e];
        short8 b1l = *(const short8*)&H1L[e];
        acc = __builtin_amdgcn_mfma_f32_16x16x32_bf16(wihh[k2], b0h, acc, 0, 0, 0);
        acc = __builtin_amdgcn_mfma_f32_16x16x32_bf16(wihl[k2], b0h, acc, 0, 0, 0);
        acc = __builtin_amdgcn_mfma_f32_16x16x32_bf16(wihh[k2], b0l, acc, 0, 0, 0);
        acc = __builtin_amdgcn_mfma_f32_16x16x32_bf16(whhh[k2], b1h, acc, 0, 0, 0);
        acc = __builtin_amdgcn_mfma_f32_16x16x32_bf16(whhl[k2], b1h, acc, 0, 0, 0);
        acc = __builtin_amdgcn_mfma_f32_16x16x32_bf16(whhh[k2], b1l, acc, 0, 0, 0);
      }
      *(f32x4*)&gsm[(wv * 16 + cl) * 16 + kq * 4] = acc;
      __syncthreads();
      if (tid < 64) {
        float gv[4];
        #pragma unroll
        for (int g = 0; g < 4; ++g) {
          int mtg = g >> 1, r = (g & 1) * 8 + ejl;
          gv[g] = gsm[(mtg * 16 + eb) * 16 + r] + gsm[((2 + mtg) * 16 + eb) * 16 + r];
        }
        float gi = gv[0] + bs0, gf = gv[1] + bs1, gg = gv[2] + bs2, go = gv[3] + bs3;
        float cn = sigf(gf) * creg + sigf(gi) * ftanh(gg);
        float hn = sigf(go) * ftanh(cn);
        creg = cn;
        int jg = j0 + ejl;
        unsigned hv = (__float_as_uint(hn) & ~0xFFu) | (unsigned)p;
        astore(h1s + (size_t)p * 4096 + eb * 512 + jg, hv);
        hdec[((size_t)eb * Usz + (p - 1)) * Kd + jg] = __uint_as_float(hv);
      }
      __syncthreads();
    }
  }
}

// W_out fp32 -> bf16, padded to 1024 rows (zeros)
__global__ __launch_bounds__(256) void k_wcvt(const float* __restrict__ W,
                                              unsigned short* __restrict__ Wb) {
  int idx = blockIdx.x * 256 + threadIdx.x;   // < 1024*512
  int n = idx >> 9;
  float v = (n < OD) ? W[idx] : 0.0f;
  Wb[idx] = f2bf(v);
}

// out[m][n] = tanh(z_enc[b,t]+z_dec[b,u]) @ Wout^T + b_out
__global__ __launch_bounds__(256, 2) void k_joint(const float* __restrict__ zenc,
                                                  const float* __restrict__ zdec,
                                                  const unsigned short* __restrict__ Wb,
                                                  const float* __restrict__ bout,
                                                  float* __restrict__ out) {
  __shared__ unsigned short Blds[32 * 512];    // 32 KB, swizzled
  int lane = threadIdx.x & 63;
  int wv = threadIdx.x >> 6;
  int kgrp = lane >> 4;
  int rl = lane & 15;
  int rbase = blockIdx.x * 128 + wv * 32;

  short8 a[2][16];
  #pragma unroll
  for (int rg = 0; rg < 2; ++rg) {
    int row = rbase + rg * 16 + rl;
    int u = row % Usz;
    int bt = row / Usz;
    const float* ze = zenc + (size_t)bt * Kd;
    const float* zd = zdec + (size_t)((bt / Tsz) * Usz + u) * Kd;
    #pragma unroll
    for (int kk = 0; kk < 16; ++kk) {
      int k0 = kk * 32 + kgrp * 8;
      float4 e0 = *(const float4*)(ze + k0);
      float4 e1 = *(const float4*)(ze + k0 + 4);
      float4 d0 = *(const float4*)(zd + k0);
      float4 d1 = *(const float4*)(zd + k0 + 4);
      short8 tt;
      tt[0] = (short)f2bf(ftanh(e0.x + d0.x));
      tt[1] = (short)f2bf(ftanh(e0.y + d0.y));
      tt[2] = (short)f2bf(ftanh(e0.z + d0.z));
      tt[3] = (short)f2bf(ftanh(e0.w + d0.w));
      tt[4] = (short)f2bf(ftanh(e1.x + d1.x));
      tt[5] = (short)f2bf(ftanh(e1.y + d1.y));
      tt[6] = (short)f2bf(ftanh(e1.z + d1.z));
      tt[7] = (short)f2bf(ftanh(e1.w + d1.w));
      a[rg][kk] = tt;
    }
  }

  int srow = threadIdx.x >> 3;
  int sc0  = threadIdx.x & 7;
  for (int it = 0; it < 32; ++it) {
    int n0 = it * 32;
    __syncthreads();
    {
      const unsigned short* src = Wb + ((size_t)(n0 + srow) << 9);
      #pragma unroll
      for (int i = 0; i < 8; ++i) {
        int c = sc0 + i * 8;
        int off = ((c * 16) ^ ((srow & 7) << 4)) + srow * 1024;
        *(int4*)((char*)Blds + off) = *(const int4*)(src + c * 8);
      }
    }
    __syncthreads();
    f32x4 acc00 = {0.f,0.f,0.f,0.f}, acc01 = {0.f,0.f,0.f,0.f};
    f32x4 acc10 = {0.f,0.f,0.f,0.f}, acc11 = {0.f,0.f,0.f,0.f};
    #pragma unroll
    for (int kk = 0; kk < 16; ++kk) {
      int c = kk * 4 + kgrp;
      int b0 = ((c * 16) ^ ((rl & 7) << 4)) + rl * 1024;
      int b1 = ((c * 16) ^ (((rl + 16) & 7) << 4)) + (rl + 16) * 1024;
      short8 bf0 = *(const short8*)((const char*)Blds + b0);
      short8 bf1 = *(const short8*)((const char*)Blds + b1);
      acc00 = __builtin_amdgcn_mfma_f32_16x16x32_bf16(a[0][kk], bf0, acc00, 0, 0, 0);
      acc10 = __builtin_amdgcn_mfma_f32_16x16x32_bf16(a[1][kk], bf0, acc10, 0, 0, 0);
      acc01 = __builtin_amdgcn_mfma_f32_16x16x32_bf16(a[0][kk], bf1, acc01, 0, 0, 0);
      acc11 = __builtin_amdgcn_mfma_f32_16x16x32_bf16(a[1][kk], bf1, acc11, 0, 0, 0);
    }
    #pragma unroll
    for (int nt = 0; nt < 2; ++nt) {
      int n = n0 + nt * 16 + rl;
      if (n < OD) {
        float bo = bout[n];
        const f32x4& A0 = nt ? acc01 : acc00;
        const f32x4& A1 = nt ? acc11 : acc10;
        size_t r0 = (size_t)(rbase + kgrp * 4) * OD + n;
        size_t r1 = (size_t)(rbase + 16 + kgrp * 4) * OD + n;
        #pragma unroll
        for (int j = 0; j < 4; ++j) {
          out[r0 + (size_t)j * OD] = A0[j] + bo;
          out[r1 + (size_t)j * OD] = A1[j] + bo;
        }
      }
    }
  }
}

extern "C" void kernel_launch(void* const* d_in, const int* in_sizes, int n_in,
                              void* d_out, int out_size, void* d_ws, size_t ws_size,
                              hipStream_t stream) {
  const float* hs   = (const float*)d_in[0];
  const int*   ys   = (const int*)d_in[1];
  const float* emb  = (const float*)d_in[2];
  const float* Wih0 = (const float*)d_in[3];
  const float* Whh0 = (const float*)d_in[4];
  const float* bih0 = (const float*)d_in[5];
  const float* bhh0 = (const float*)d_in[6];
  const float* Wih1 = (const float*)d_in[7];
  const float* Whh1 = (const float*)d_in[8];
  const float* bih1 = (const float*)d_in[9];
  const float* bhh1 = (const float*)d_in[10];
  const float* Wenc = (const float*)d_in[11];
  const float* benc = (const float*)d_in[12];
  const float* Wdec = (const float*)d_in[13];
  const float* Wout = (const float*)d_in[14];
  const float* bout = (const float*)d_in[15];
  float* out = (float*)d_out;

  // layout (floats), no overlaps; total 2,932,736 floats = 11.73 MB
  float* ws   = (float*)d_ws;
  float* eys  = ws;                       // [0,       204800)
  float* xgr  = ws + 204800;              // [204800, 1024000)  [u][jb][g][jl*8+b]
  float* zenc = ws + 1024000;             // [1024000,1843200)
  float* zdec = ws + 1843200;             // [1843200,2048000)
  float* hdec = ws + 2048000;             // [2048000,2252800)  [b][u][512]
  unsigned short* Wb = (unsigned short*)(ws + 2252800);  // 1024*512 bf16 = [2252800,2514944)
  unsigned* h0s = (unsigned*)(ws + 2514944);  // 51*4096 u32 = [2514944,2723840)
  unsigned* h1s = (unsigned*)(ws + 2723840);  // 51*4096 u32 = [2723840,2932736)

  k_init<<<16, 256, 0, stream>>>(h0s, h1s);
  k_embed<<<400, 256, 0, stream>>>(ys, emb, eys);
  k_gemm_xg<<<dim3(25, 32), 256, 0, stream>>>(eys, Wih0, bih0, bhh0, xgr);
  k_gemm<<<dim3(100, 8), 256, 0, stream>>>(hs, Wenc, benc, nullptr, zenc, 512);
  k_wcvt<<<2048, 256, 0, stream>>>(Wout, Wb);
  k_lstm_all<<<96, 256, 0, stream>>>(Whh0, Wih1, Whh1, bih1, bhh1, xgr,
                                     h0s, h1s, hdec);
  k_gemm<<<dim3(25, 8), 256, 0, stream>>>(hdec, Wdec, nullptr, nullptr, zdec, 512);
  k_joint<<<625, 256, 0, stream>>>(zenc, zdec, Wb, bout, out);
}